// Round 5
// baseline (442.571 us; speedup 1.0000x reference)
//
#include <hip/hip_runtime.h>
#include <hip/hip_bf16.h>

typedef __hip_bfloat16 bf16;
typedef __bf16 bf16x8 __attribute__((ext_vector_type(8)));
typedef float f32x4 __attribute__((ext_vector_type(4)));
typedef float f32x16 __attribute__((ext_vector_type(16)));
typedef unsigned int u32;

typedef const __attribute__((address_space(1))) void GV;
typedef __attribute__((address_space(3))) void LV;

#define TM 128
#define TN 128
#define TK 64

static __device__ __forceinline__ float fexp2(float x) {
#if __has_builtin(__builtin_amdgcn_exp2f)
    return __builtin_amdgcn_exp2f(x);
#else
    return exp2f(x);
#endif
}

// ---------------- cast fp32 -> bf16 (4 elems/thread) ----------------
__global__ void cast_k(const float* __restrict__ src, bf16* __restrict__ dst, int n4) {
    int i = blockIdx.x * 256 + threadIdx.x;
    if (i >= n4) return;
    float4 a = reinterpret_cast<const float4*>(src)[i];
    bf16* d = dst + (size_t)i * 4;
    d[0] = __float2bfloat16(a.x);
    d[1] = __float2bfloat16(a.y);
    d[2] = __float2bfloat16(a.z);
    d[3] = __float2bfloat16(a.w);
}

// ---------------- repack sr_w [co][ci][kh][kw] -> [co][p*512+ci] bf16 ----------------
__global__ void repack_srw_k(const float* __restrict__ srw, bf16* __restrict__ dst) {
    int idx = blockIdx.x * 256 + threadIdx.x;   // 512*2048 = 1<<20
    int co = idx >> 11;
    int t  = idx & 2047;
    int p  = t >> 9;        // kh*2+kw
    int ci = t & 511;
    dst[idx] = __float2bfloat16(srw[(size_t)co * 2048 + ci * 4 + p]);
}

// ---------------- generic bf16 GEMM, m97 structure ----------------
template<int KIND>
__launch_bounds__(256)
__global__ void gemm_k(const bf16* __restrict__ A, const bf16* __restrict__ Bw,
                       const float* __restrict__ bias,
                       bf16* __restrict__ outB, bf16* __restrict__ outB2,
                       float* __restrict__ outF,
                       int M, int N, int K) {
    __shared__ __align__(16) bf16 ldsA[TM * TK];
    __shared__ __align__(16) bf16 ldsB[TN * TK];
    const int tid = threadIdx.x;
    const int lane = tid & 63;
    const int wave = tid >> 6;
    const int ntn = N / TN;
    const int row0 = (blockIdx.x / ntn) * TM;
    const int col0 = (blockIdx.x % ntn) * TN;
    const int wm = wave >> 1, wn = wave & 1;

    f32x4 acc[4][4];
#pragma unroll
    for (int i = 0; i < 4; ++i)
#pragma unroll
        for (int j = 0; j < 4; ++j) acc[i][j] = f32x4{0.f, 0.f, 0.f, 0.f};

    for (int k0 = 0; k0 < K; k0 += TK) {
#pragma unroll
        for (int t = 0; t < 4; ++t) {
            int idx = t * 256 + tid;
            int r = idx >> 3;
            int c = (idx & 7) * 8;
            const bf16* src;
            if (KIND == 1) {
                int rr = row0 + r;
                int k = k0 + c;
                int p = k >> 9, ci = k & 511;
                int b = rr >> 10, ii = (rr >> 5) & 31, jj = rr & 31;
                int n_in = (2 * ii + (p >> 1)) * 64 + 2 * jj + (p & 1);
                src = A + ((size_t)(b * 4096 + n_in)) * 512 + ci;
            } else {
                src = A + (size_t)(row0 + r) * K + k0 + c;
            }
            __builtin_amdgcn_global_load_lds((GV*)src, (LV*)&ldsA[idx * 8], 16, 0, 0);
        }
#pragma unroll
        for (int t = 0; t < 4; ++t) {
            int idx = t * 256 + tid;
            int r = idx >> 3;
            int c = (idx & 7) * 8;
            const bf16* src = Bw + (size_t)(col0 + r) * K + k0 + c;
            __builtin_amdgcn_global_load_lds((GV*)src, (LV*)&ldsB[idx * 8], 16, 0, 0);
        }
        __syncthreads();
#pragma unroll
        for (int kk = 0; kk < 2; ++kk) {
            const int kb = kk * 32 + (lane >> 4) * 8;
            bf16x8 af[4], bfr[4];
#pragma unroll
            for (int m = 0; m < 4; ++m)
                af[m] = *reinterpret_cast<const bf16x8*>(&ldsA[(wm * 64 + m * 16 + (lane & 15)) * TK + kb]);
#pragma unroll
            for (int n = 0; n < 4; ++n)
                bfr[n] = *reinterpret_cast<const bf16x8*>(&ldsB[(wn * 64 + n * 16 + (lane & 15)) * TK + kb]);
#pragma unroll
            for (int m = 0; m < 4; ++m)
#pragma unroll
                for (int n = 0; n < 4; ++n)
                    acc[m][n] = __builtin_amdgcn_mfma_f32_16x16x32_bf16(af[m], bfr[n], acc[m][n], 0, 0, 0);
        }
        __syncthreads();
    }

#pragma unroll
    for (int m = 0; m < 4; ++m) {
#pragma unroll
        for (int n = 0; n < 4; ++n) {
#pragma unroll
            for (int r = 0; r < 4; ++r) {
                int grow = row0 + wm * 64 + m * 16 + (lane >> 4) * 4 + r;
                int gcol = col0 + wn * 64 + n * 16 + (lane & 15);
                float v = acc[m][n][r] + bias[gcol];
                if (KIND == 0) {
                    int b = grow >> 12, nn = grow & 4095;
                    int h = gcol >> 6, dd = gcol & 63;
                    // scale = 1/8 * log2(e): softmax computed in exp2 domain
                    outB[(((size_t)(b * 8 + h)) * 4096 + nn) * 64 + dd] =
                        __float2bfloat16(v * 0.18033688011112042f);
                } else if (KIND == 1) {
                    outF[(size_t)grow * 512 + gcol] = v;
                } else if (KIND == 2) {
                    int b = grow >> 10, mm = grow & 1023;
                    if (gcol < 512) {
                        int h = gcol >> 6, dd = gcol & 63;
                        outB[(((size_t)(b * 8 + h)) * 1024 + mm) * 64 + dd] = __float2bfloat16(v);
                    } else {
                        int c2 = gcol - 512;
                        int h = c2 >> 6, dd = c2 & 63;
                        outB2[(((size_t)(b * 8 + h)) * 64 + dd) * 1024 + mm] = __float2bfloat16(v);
                    }
                } else {
                    outF[(size_t)grow * 512 + gcol] = v;
                }
            }
        }
    }
}

// ---------------- layernorm (fp32 in -> bf16 out), one block per row ----------------
__global__ void ln_k(const float* __restrict__ xsr, const float* __restrict__ g,
                     const float* __restrict__ bta, bf16* __restrict__ out) {
    const int row = blockIdx.x;
    const int tid = threadIdx.x;          // 256
    const float* xr = xsr + (size_t)row * 512;
    float2 v = *reinterpret_cast<const float2*>(xr + tid * 2);
    float s = v.x + v.y;
    float sq = v.x * v.x + v.y * v.y;
#pragma unroll
    for (int m = 1; m < 64; m <<= 1) {
        s += __shfl_xor(s, m, 64);
        sq += __shfl_xor(sq, m, 64);
    }
    __shared__ float rs[4], rq[4];
    int wave = tid >> 6, lane = tid & 63;
    if (lane == 0) { rs[wave] = s; rq[wave] = sq; }
    __syncthreads();
    s = rs[0] + rs[1] + rs[2] + rs[3];
    sq = rq[0] + rq[1] + rq[2] + rq[3];
    float mu = s * (1.f / 512.f);
    float var = sq * (1.f / 512.f) - mu * mu;
    float rstd = rsqrtf(var + 1e-5f);
    bf16* orow = out + (size_t)row * 512;
    orow[tid * 2]     = __float2bfloat16((v.x - mu) * rstd * g[tid * 2] + bta[tid * 2]);
    orow[tid * 2 + 1] = __float2bfloat16((v.y - mu) * rstd * g[tid * 2 + 1] + bta[tid * 2 + 1]);
}

// ---------------- flash attention v5: full-register pipeline (256-VGPR budget) ----------------
// Q: [bh][n][64] (pre-scaled by 1/8*log2e), K: [bh][m][64], Vt: [bh][64][m], Out: [b][n][512]
__launch_bounds__(256, 2)
__global__ void attn_k(const bf16* __restrict__ Q, const bf16* __restrict__ Kb,
                       const bf16* __restrict__ Vt, bf16* __restrict__ Out) {
    // XCD-pinned swizzle: p%8 selects the XCD (round-robin dispatch) -> each XCD's
    // resident blocks share 1-2 bh values (256-512 KB K/V) fitting its 4 MB L2.
    const int p = blockIdx.x;                  // 2048 blocks
    const int bh = (p & 7) * 8 + (p >> 8);     // [0,64)
    const int qb = (p >> 3) & 31;              // [0,32)
    const int b = bh >> 3, h = bh & 7;
    const int tid = threadIdx.x, lane = tid & 63, wave = tid >> 6;
    const int q0 = qb * 128 + wave * 32;
    const int l31 = lane & 31;
    const int klo8 = (lane >> 5) * 8;
    const bool hi = lane >= 32;

    const bf16* Qp = Q + ((size_t)bh * 4096 + q0) * 64;
    const bf16* Kp = Kb + (size_t)bh * 1024 * 64;
    const bf16* Vp = Vt + (size_t)bh * 64 * 1024;

    // Q fragments (B-operand of swapped QK^T): col=query=l31, k=d contiguous
    bf16x8 qf[4];
#pragma unroll
    for (int c = 0; c < 4; ++c)
        qf[c] = *reinterpret_cast<const bf16x8*>(Qp + (size_t)l31 * 64 + c * 16 + klo8);

    const bf16* kRow  = Kp + (size_t)l31 * 64 + klo8;
    const bf16* vRow0 = Vp + (size_t)l31 * 1024 + klo8;
    const bf16* vRow1 = Vp + (size_t)(32 + l31) * 1024 + klo8;

    f32x16 accO[2];
    accO[0] = f32x16{};
    accO[1] = f32x16{};
    float mrun = -1e30f;
    float lrun = 0.f;                 // per half-lane; combined after the loop

    // prologue: K tile 0 -> QK for tile 0
    f32x16 s_cur = f32x16{};
    {
        bf16x8 k0[4];
#pragma unroll
        for (int c = 0; c < 4; ++c)
            k0[c] = *reinterpret_cast<const bf16x8*>(kRow + c * 16);
#pragma unroll
        for (int c = 0; c < 4; ++c)
            s_cur = __builtin_amdgcn_mfma_f32_32x32x16_bf16(k0[c], qf[c], s_cur, 0, 0, 0);
    }

    for (int kt = 0; kt < 1024; kt += 32) {
        const int ktn = kt + 32;
        const bool more = (ktn < 1024);

        // issue next-tile K loads + this-tile V loads early; all 8 in flight,
        // latency hides under softmax below (registers now exist: 256-VGPR budget).
        bf16x8 kfn[4], vv[4];
        if (more) {
#pragma unroll
            for (int c = 0; c < 4; ++c)
                kfn[c] = *reinterpret_cast<const bf16x8*>(kRow + (size_t)ktn * 64 + c * 16);
        }
        vv[0] = *reinterpret_cast<const bf16x8*>(vRow0 + kt);
        vv[1] = *reinterpret_cast<const bf16x8*>(vRow0 + kt + 16);
        vv[2] = *reinterpret_cast<const bf16x8*>(vRow1 + kt);
        vv[3] = *reinterpret_cast<const bf16x8*>(vRow1 + kt + 16);

        // ---- softmax on s_cur (log2 domain) ----
        float t0 = fmaxf(fmaxf(s_cur[0], s_cur[1]), fmaxf(s_cur[2], s_cur[3]));
        float t1 = fmaxf(fmaxf(s_cur[4], s_cur[5]), fmaxf(s_cur[6], s_cur[7]));
        float t2 = fmaxf(fmaxf(s_cur[8], s_cur[9]), fmaxf(s_cur[10], s_cur[11]));
        float t3 = fmaxf(fmaxf(s_cur[12], s_cur[13]), fmaxf(s_cur[14], s_cur[15]));
        float mt = fmaxf(fmaxf(t0, t1), fmaxf(t2, t3));
        mt = fmaxf(mt, __shfl_xor(mt, 32, 64));

        // defer-max (T13): only rescale when the max grew by > 8 (log2 units)
        if (!__all(mt - mrun <= 8.f)) {
            float mn = fmaxf(mrun, mt);
            float fac = fexp2(mrun - mn);
            lrun *= fac;
#pragma unroll
            for (int dd = 0; dd < 2; ++dd)
#pragma unroll
                for (int r = 0; r < 16; ++r) accO[dd][r] *= fac;
            mrun = mn;
        }

        // P = 2^(S - m), 4-way partial sums for ILP
        float pr[16];
#pragma unroll
        for (int r = 0; r < 16; ++r) pr[r] = fexp2(s_cur[r] - mrun);
        float a0 = (pr[0] + pr[1]) + (pr[2] + pr[3]);
        float a1 = (pr[4] + pr[5]) + (pr[6] + pr[7]);
        float a2 = (pr[8] + pr[9]) + (pr[10] + pr[11]);
        float a3 = (pr[12] + pr[13]) + (pr[14] + pr[15]);
        lrun += (a0 + a1) + (a2 + a3);

        // pack to bf16 pairs
        u32 w[8];
#pragma unroll
        for (int k = 0; k < 8; ++k) {
            union { __hip_bfloat162 h2; u32 u; } cv;
            cv.h2 = __float22bfloat162_rn(float2{pr[2 * k], pr[2 * k + 1]});
            w[k] = cv.u;
        }
        // cross-half exchange: each lane fetches exactly the 4 partner words it needs
        u32 y0 = __shfl_xor(hi ? w[0] : w[2], 32, 64);
        u32 y1 = __shfl_xor(hi ? w[1] : w[3], 32, 64);
        u32 y2 = __shfl_xor(hi ? w[4] : w[6], 32, 64);
        u32 y3 = __shfl_xor(hi ? w[5] : w[7], 32, 64);

        union { u32 u[4]; bf16x8 v; } f0, f1;
        f0.u[0] = hi ? y0 : w[0];
        f0.u[1] = hi ? y1 : w[1];
        f0.u[2] = hi ? w[2] : y0;
        f0.u[3] = hi ? w[3] : y1;
        f1.u[0] = hi ? y2 : w[4];
        f1.u[1] = hi ? y3 : w[5];
        f1.u[2] = hi ? w[6] : y2;
        f1.u[3] = hi ? w[7] : y3;

        // ---- MFMA cluster: QK(t+1) then PV(t) ----
        __builtin_amdgcn_s_setprio(1);
        f32x16 s_next = f32x16{};
        if (more) {
#pragma unroll
            for (int c = 0; c < 4; ++c)
                s_next = __builtin_amdgcn_mfma_f32_32x32x16_bf16(kfn[c], qf[c], s_next, 0, 0, 0);
        }
        accO[0] = __builtin_amdgcn_mfma_f32_32x32x16_bf16(vv[0], f0.v, accO[0], 0, 0, 0);
        accO[0] = __builtin_amdgcn_mfma_f32_32x32x16_bf16(vv[1], f1.v, accO[0], 0, 0, 0);
        accO[1] = __builtin_amdgcn_mfma_f32_32x32x16_bf16(vv[2], f0.v, accO[1], 0, 0, 0);
        accO[1] = __builtin_amdgcn_mfma_f32_32x32x16_bf16(vv[3], f1.v, accO[1], 0, 0, 0);
        __builtin_amdgcn_s_setprio(0);

        s_cur = s_next;
    }

    // combine per-half sums once
    lrun += __shfl_xor(lrun, 32, 64);

    // epilogue: O^T (d-major in regs) -> LDS [q][d] -> coalesced global store
    __shared__ __align__(16) bf16 obuf[4][32][72];
    float inv = 1.f / lrun;
#pragma unroll
    for (int dd = 0; dd < 2; ++dd)
#pragma unroll
        for (int r = 0; r < 16; r += 2) {
            int d = dd * 32 + (r & 3) + 8 * (r >> 2) + 4 * (lane >> 5);
            union { __hip_bfloat162 h2; u32 u; } cv;
            cv.h2 = __float22bfloat162_rn(float2{accO[dd][r] * inv, accO[dd][r + 1] * inv});
            *reinterpret_cast<u32*>(&obuf[wave][l31][d]) = cv.u;
        }
    __syncthreads();
    {
        int qr = lane >> 1, hf = lane & 1;
        const bf16* orow = &obuf[wave][qr][hf * 32];
        bf16* gout = Out + ((size_t)b * 4096 + q0 + qr) * 512 + h * 64 + hf * 32;
#pragma unroll
        for (int j = 0; j < 4; ++j) {
            bf16x8 t = *reinterpret_cast<const bf16x8*>(orow + j * 8);
            *reinterpret_cast<bf16x8*>(gout + j * 8) = t;
        }
    }
}

extern "C" void kernel_launch(void* const* d_in, const int* in_sizes, int n_in,
                              void* d_out, int out_size, void* d_ws, size_t ws_size,
                              hipStream_t stream) {
    const float* x      = (const float*)d_in[0];
    const float* q_w    = (const float*)d_in[1];
    const float* q_b    = (const float*)d_in[2];
    const float* kv_w   = (const float*)d_in[3];
    const float* kv_b   = (const float*)d_in[4];
    const float* sr_w   = (const float*)d_in[5];
    const float* sr_b   = (const float*)d_in[6];
    const float* ln_g   = (const float*)d_in[7];
    const float* ln_b   = (const float*)d_in[8];
    const float* proj_w = (const float*)d_in[9];
    const float* proj_b = (const float*)d_in[10];

    char* w = (char*)d_ws;
    bf16* x_bf   = (bf16*)w; w += (size_t)8 * 4096 * 512 * 2;
    bf16* q_bf   = (bf16*)w; w += (size_t)8 * 4096 * 512 * 2;
    bf16* qw_bf  = (bf16*)w; w += (size_t)512 * 512 * 2;
    bf16* kvw_bf = (bf16*)w; w += (size_t)1024 * 512 * 2;
    bf16* srw_bf = (bf16*)w; w += (size_t)512 * 2048 * 2;
    bf16* pjw_bf = (bf16*)w; w += (size_t)512 * 512 * 2;
    float* xsr_f = (float*)w; w += (size_t)8 * 1024 * 512 * 4;
    bf16* xsrb   = (bf16*)w; w += (size_t)8 * 1024 * 512 * 2;
    bf16* k_bf   = (bf16*)w; w += (size_t)8 * 8 * 1024 * 64 * 2;
    bf16* vt_bf  = (bf16*)w; w += (size_t)8 * 8 * 1024 * 64 * 2;
    bf16* ao_bf  = (bf16*)w; w += (size_t)8 * 4096 * 512 * 2;

    cast_k<<<dim3(16384), dim3(256), 0, stream>>>(x, x_bf, 4194304);
    cast_k<<<dim3(256),  dim3(256), 0, stream>>>(q_w, qw_bf, 65536);
    cast_k<<<dim3(512),  dim3(256), 0, stream>>>(kv_w, kvw_bf, 131072);
    cast_k<<<dim3(256),  dim3(256), 0, stream>>>(proj_w, pjw_bf, 65536);
    repack_srw_k<<<dim3(4096), dim3(256), 0, stream>>>(sr_w, srw_bf);

    gemm_k<0><<<dim3(1024), dim3(256), 0, stream>>>(x_bf, qw_bf, q_b, q_bf, nullptr, nullptr, 32768, 512, 512);
    gemm_k<1><<<dim3(256), dim3(256), 0, stream>>>(x_bf, srw_bf, sr_b, nullptr, nullptr, xsr_f, 8192, 512, 2048);
    ln_k<<<dim3(8192), dim3(256), 0, stream>>>(xsr_f, ln_g, ln_b, xsrb);
    gemm_k<2><<<dim3(512), dim3(256), 0, stream>>>(xsrb, kvw_bf, kv_b, k_bf, vt_bf, nullptr, 8192, 1024, 512);
    attn_k<<<dim3(2048), dim3(256), 0, stream>>>(q_bf, k_bf, vt_bf, ao_bf);
    gemm_k<3><<<dim3(1024), dim3(256), 0, stream>>>(ao_bf, pjw_bf, proj_b, nullptr, nullptr, (float*)d_out, 32768, 512, 512);
}

// Round 6
// 296.646 us; speedup vs baseline: 1.4919x; 1.4919x over previous
//
#include <hip/hip_runtime.h>
#include <hip/hip_bf16.h>

typedef __hip_bfloat16 bf16;
typedef __bf16 bf16x8 __attribute__((ext_vector_type(8)));
typedef float f32x4 __attribute__((ext_vector_type(4)));
typedef float f32x16 __attribute__((ext_vector_type(16)));
typedef unsigned int u32;

typedef const __attribute__((address_space(1))) void GV;
typedef __attribute__((address_space(3))) void LV;

#define TM 128
#define TN 128
#define TK 64

static __device__ __forceinline__ float fexp2(float x) {
#if __has_builtin(__builtin_amdgcn_exp2f)
    return __builtin_amdgcn_exp2f(x);
#else
    return exp2f(x);
#endif
}

// ---------------- cast fp32 -> bf16 (4 elems/thread) ----------------
__global__ void cast_k(const float* __restrict__ src, bf16* __restrict__ dst, int n4) {
    int i = blockIdx.x * 256 + threadIdx.x;
    if (i >= n4) return;
    float4 a = reinterpret_cast<const float4*>(src)[i];
    bf16* d = dst + (size_t)i * 4;
    d[0] = __float2bfloat16(a.x);
    d[1] = __float2bfloat16(a.y);
    d[2] = __float2bfloat16(a.z);
    d[3] = __float2bfloat16(a.w);
}

// ---------------- repack sr_w [co][ci][kh][kw] -> [co][p*512+ci] bf16 ----------------
__global__ void repack_srw_k(const float* __restrict__ srw, bf16* __restrict__ dst) {
    int idx = blockIdx.x * 256 + threadIdx.x;   // 512*2048 = 1<<20
    int co = idx >> 11;
    int t  = idx & 2047;
    int p  = t >> 9;        // kh*2+kw
    int ci = t & 511;
    dst[idx] = __float2bfloat16(srw[(size_t)co * 2048 + ci * 4 + p]);
}

// ---------------- generic bf16 GEMM, m97 structure ----------------
template<int KIND>
__launch_bounds__(256)
__global__ void gemm_k(const bf16* __restrict__ A, const bf16* __restrict__ Bw,
                       const float* __restrict__ bias,
                       bf16* __restrict__ outB, bf16* __restrict__ outB2,
                       float* __restrict__ outF,
                       int M, int N, int K) {
    __shared__ __align__(16) bf16 ldsA[TM * TK];
    __shared__ __align__(16) bf16 ldsB[TN * TK];
    const int tid = threadIdx.x;
    const int lane = tid & 63;
    const int wave = tid >> 6;
    const int ntn = N / TN;
    const int row0 = (blockIdx.x / ntn) * TM;
    const int col0 = (blockIdx.x % ntn) * TN;
    const int wm = wave >> 1, wn = wave & 1;

    f32x4 acc[4][4];
#pragma unroll
    for (int i = 0; i < 4; ++i)
#pragma unroll
        for (int j = 0; j < 4; ++j) acc[i][j] = f32x4{0.f, 0.f, 0.f, 0.f};

    for (int k0 = 0; k0 < K; k0 += TK) {
#pragma unroll
        for (int t = 0; t < 4; ++t) {
            int idx = t * 256 + tid;
            int r = idx >> 3;
            int c = (idx & 7) * 8;
            const bf16* src;
            if (KIND == 1) {
                int rr = row0 + r;
                int k = k0 + c;
                int p = k >> 9, ci = k & 511;
                int b = rr >> 10, ii = (rr >> 5) & 31, jj = rr & 31;
                int n_in = (2 * ii + (p >> 1)) * 64 + 2 * jj + (p & 1);
                src = A + ((size_t)(b * 4096 + n_in)) * 512 + ci;
            } else {
                src = A + (size_t)(row0 + r) * K + k0 + c;
            }
            __builtin_amdgcn_global_load_lds((GV*)src, (LV*)&ldsA[idx * 8], 16, 0, 0);
        }
#pragma unroll
        for (int t = 0; t < 4; ++t) {
            int idx = t * 256 + tid;
            int r = idx >> 3;
            int c = (idx & 7) * 8;
            const bf16* src = Bw + (size_t)(col0 + r) * K + k0 + c;
            __builtin_amdgcn_global_load_lds((GV*)src, (LV*)&ldsB[idx * 8], 16, 0, 0);
        }
        __syncthreads();
#pragma unroll
        for (int kk = 0; kk < 2; ++kk) {
            const int kb = kk * 32 + (lane >> 4) * 8;
            bf16x8 af[4], bfr[4];
#pragma unroll
            for (int m = 0; m < 4; ++m)
                af[m] = *reinterpret_cast<const bf16x8*>(&ldsA[(wm * 64 + m * 16 + (lane & 15)) * TK + kb]);
#pragma unroll
            for (int n = 0; n < 4; ++n)
                bfr[n] = *reinterpret_cast<const bf16x8*>(&ldsB[(wn * 64 + n * 16 + (lane & 15)) * TK + kb]);
#pragma unroll
            for (int m = 0; m < 4; ++m)
#pragma unroll
                for (int n = 0; n < 4; ++n)
                    acc[m][n] = __builtin_amdgcn_mfma_f32_16x16x32_bf16(af[m], bfr[n], acc[m][n], 0, 0, 0);
        }
        __syncthreads();
    }

#pragma unroll
    for (int m = 0; m < 4; ++m) {
#pragma unroll
        for (int n = 0; n < 4; ++n) {
#pragma unroll
            for (int r = 0; r < 4; ++r) {
                int grow = row0 + wm * 64 + m * 16 + (lane >> 4) * 4 + r;
                int gcol = col0 + wn * 64 + n * 16 + (lane & 15);
                float v = acc[m][n][r] + bias[gcol];
                if (KIND == 0) {
                    int b = grow >> 12, nn = grow & 4095;
                    int h = gcol >> 6, dd = gcol & 63;
                    // scale = 1/8 * log2(e): softmax computed in exp2 domain
                    outB[(((size_t)(b * 8 + h)) * 4096 + nn) * 64 + dd] =
                        __float2bfloat16(v * 0.18033688011112042f);
                } else if (KIND == 1) {
                    outF[(size_t)grow * 512 + gcol] = v;
                } else if (KIND == 2) {
                    int b = grow >> 10, mm = grow & 1023;
                    if (gcol < 512) {
                        int h = gcol >> 6, dd = gcol & 63;
                        outB[(((size_t)(b * 8 + h)) * 1024 + mm) * 64 + dd] = __float2bfloat16(v);
                    } else {
                        int c2 = gcol - 512;
                        int h = c2 >> 6, dd = c2 & 63;
                        outB2[(((size_t)(b * 8 + h)) * 64 + dd) * 1024 + mm] = __float2bfloat16(v);
                    }
                } else {
                    outF[(size_t)grow * 512 + gcol] = v;
                }
            }
        }
    }
}

// ---------------- layernorm (fp32 in -> bf16 out), one block per row ----------------
__global__ void ln_k(const float* __restrict__ xsr, const float* __restrict__ g,
                     const float* __restrict__ bta, bf16* __restrict__ out) {
    const int row = blockIdx.x;
    const int tid = threadIdx.x;          // 256
    const float* xr = xsr + (size_t)row * 512;
    float2 v = *reinterpret_cast<const float2*>(xr + tid * 2);
    float s = v.x + v.y;
    float sq = v.x * v.x + v.y * v.y;
#pragma unroll
    for (int m = 1; m < 64; m <<= 1) {
        s += __shfl_xor(s, m, 64);
        sq += __shfl_xor(sq, m, 64);
    }
    __shared__ float rs[4], rq[4];
    int wave = tid >> 6, lane = tid & 63;
    if (lane == 0) { rs[wave] = s; rq[wave] = sq; }
    __syncthreads();
    s = rs[0] + rs[1] + rs[2] + rs[3];
    sq = rq[0] + rq[1] + rq[2] + rq[3];
    float mu = s * (1.f / 512.f);
    float var = sq * (1.f / 512.f) - mu * mu;
    float rstd = rsqrtf(var + 1e-5f);
    bf16* orow = out + (size_t)row * 512;
    orow[tid * 2]     = __float2bfloat16((v.x - mu) * rstd * g[tid * 2] + bta[tid * 2]);
    orow[tid * 2 + 1] = __float2bfloat16((v.y - mu) * rstd * g[tid * 2 + 1] + bta[tid * 2 + 1]);
}

// ---------------- flash attention v6: LDS-staged K/V (global_load_lds), KVBLK=64 ----------------
// Q: [bh][n][64] (pre-scaled by 1/8*log2e), K: [bh][m][64], Vt: [bh][64][m], Out: [b][n][512]
// Block: 4 waves x 32 q on one bh. K/V tiles staged once per block (4x traffic cut),
// double-buffered, XOR-swizzled (linear LDS dest + pre-swizzled global source, rule #21).
__launch_bounds__(256, 2)
__global__ void attn_k(const bf16* __restrict__ Q, const bf16* __restrict__ Kb,
                       const bf16* __restrict__ Vt, bf16* __restrict__ Out) {
    const int p = blockIdx.x;                  // 2048 blocks
    const int bh = (p & 7) * 8 + (p >> 8);     // XCD-pinned
    const int qb = (p >> 3) & 31;
    const int b = bh >> 3, h = bh & 7;
    const int tid = threadIdx.x, lane = tid & 63, wave = tid >> 6;
    const int q0 = qb * 128 + wave * 32;
    const int l31 = lane & 31;
    const int klo8 = (lane >> 5) * 8;
    const bool hi = lane >= 32;
    const int sx = l31 & 7;                    // read-side XOR key

    const bf16* Qp = Q + ((size_t)bh * 4096 + q0) * 64;
    const bf16* Kp = Kb + (size_t)bh * 1024 * 64;
    const bf16* Vp = Vt + (size_t)bh * 64 * 1024;

    // smem: two 16 KB buffers; each = K-tile [64 key][64 d] (8 KB) + V-tile [64 d][64 key] (8 KB).
    // Epilogue obuf (18 KB) overlays the same region after the loop.
    __shared__ __align__(16) char smem[32768];

    // Q fragments (B-operand of swapped QK^T): col=query=l31, k=d contiguous
    bf16x8 qf[4];
#pragma unroll
    for (int c = 0; c < 4; ++c)
        qf[c] = *reinterpret_cast<const bf16x8*>(Qp + (size_t)l31 * 64 + c * 16 + klo8);

    f32x16 accO[2];
    accO[0] = f32x16{};
    accO[1] = f32x16{};
    float mrun = -1e30f;
    float lrun = 0.f;                 // per half-lane; combined after the loop

    // stage chunk helper values: this wave stages chunks c = (wave*2+i)*64 + lane
    // (16B chunks; row = c>>3, c16 = c&7, swizzled source col16 = c16 ^ (row&7)).
    const int c_i0 = wave * 2 * 64 + lane;
    const int c_i1 = (wave * 2 + 1) * 64 + lane;
    const int r0 = c_i0 >> 3, s0c = ((c_i0 & 7) ^ (r0 & 7)) * 8;
    const int r1 = c_i1 >> 3, s1c = ((c_i1 & 7) ^ (r1 & 7)) * 8;

#define STAGE_TILE(KT, BASE)                                                            \
    do {                                                                                \
        char* _b = (BASE);                                                              \
        __builtin_amdgcn_global_load_lds((GV*)(Kp + (size_t)((KT) + r0) * 64 + s0c),    \
                                         (LV*)(_b + wave * 2048), 16, 0, 0);            \
        __builtin_amdgcn_global_load_lds((GV*)(Kp + (size_t)((KT) + r1) * 64 + s1c),    \
                                         (LV*)(_b + wave * 2048 + 1024), 16, 0, 0);     \
        __builtin_amdgcn_global_load_lds((GV*)(Vp + (size_t)r0 * 1024 + (KT) + s0c),    \
                                         (LV*)(_b + 8192 + wave * 2048), 16, 0, 0);     \
        __builtin_amdgcn_global_load_lds((GV*)(Vp + (size_t)r1 * 1024 + (KT) + s1c),    \
                                         (LV*)(_b + 8192 + wave * 2048 + 1024), 16, 0, 0); \
    } while (0)

    // prologue: stage tile 0
    STAGE_TILE(0, smem);
    __syncthreads();

    int cur = 0;
    for (int t = 0; t < 16; ++t) {
        char* bcur = smem + cur * 16384;
        if (t < 15) STAGE_TILE((t + 1) * 64, smem + (cur ^ 1) * 16384);

        // ---- ds_read K fragments (swizzled) + QK^T for both 32-key halves ----
        bf16x8 kf0[4], kf1[4];
#pragma unroll
        for (int c = 0; c < 4; ++c) {
            int c16r = c * 2 + (lane >> 5);
            kf0[c] = *reinterpret_cast<const bf16x8*>(bcur + l31 * 128 + ((c16r ^ sx) * 16));
            kf1[c] = *reinterpret_cast<const bf16x8*>(bcur + (32 + l31) * 128 + ((c16r ^ sx) * 16));
        }
        f32x16 sA = f32x16{}, sB = f32x16{};
#pragma unroll
        for (int c = 0; c < 4; ++c) {
            sA = __builtin_amdgcn_mfma_f32_32x32x16_bf16(kf0[c], qf[c], sA, 0, 0, 0);
            sB = __builtin_amdgcn_mfma_f32_32x32x16_bf16(kf1[c], qf[c], sB, 0, 0, 0);
        }

        // ---- softmax over 64 keys (log2 domain) ----
        float m0 = fmaxf(fmaxf(sA[0], sA[1]), fmaxf(sA[2], sA[3]));
        float m1 = fmaxf(fmaxf(sA[4], sA[5]), fmaxf(sA[6], sA[7]));
        float m2 = fmaxf(fmaxf(sA[8], sA[9]), fmaxf(sA[10], sA[11]));
        float m3 = fmaxf(fmaxf(sA[12], sA[13]), fmaxf(sA[14], sA[15]));
        float m4 = fmaxf(fmaxf(sB[0], sB[1]), fmaxf(sB[2], sB[3]));
        float m5 = fmaxf(fmaxf(sB[4], sB[5]), fmaxf(sB[6], sB[7]));
        float m6 = fmaxf(fmaxf(sB[8], sB[9]), fmaxf(sB[10], sB[11]));
        float m7 = fmaxf(fmaxf(sB[12], sB[13]), fmaxf(sB[14], sB[15]));
        float mt = fmaxf(fmaxf(fmaxf(m0, m1), fmaxf(m2, m3)),
                         fmaxf(fmaxf(m4, m5), fmaxf(m6, m7)));
        mt = fmaxf(mt, __shfl_xor(mt, 32, 64));

        if (!__all(mt - mrun <= 8.f)) {
            float mn = fmaxf(mrun, mt);
            float fac = fexp2(mrun - mn);
            lrun *= fac;
#pragma unroll
            for (int dd = 0; dd < 2; ++dd)
#pragma unroll
                for (int r = 0; r < 16; ++r) accO[dd][r] *= fac;
            mrun = mn;
        }

        float pA[16], pB[16];
#pragma unroll
        for (int r = 0; r < 16; ++r) pA[r] = fexp2(sA[r] - mrun);
#pragma unroll
        for (int r = 0; r < 16; ++r) pB[r] = fexp2(sB[r] - mrun);
        float a0 = (pA[0] + pA[1]) + (pA[2] + pA[3]);
        float a1 = (pA[4] + pA[5]) + (pA[6] + pA[7]);
        float a2 = (pA[8] + pA[9]) + (pA[10] + pA[11]);
        float a3 = (pA[12] + pA[13]) + (pA[14] + pA[15]);
        float a4 = (pB[0] + pB[1]) + (pB[2] + pB[3]);
        float a5 = (pB[4] + pB[5]) + (pB[6] + pB[7]);
        float a6 = (pB[8] + pB[9]) + (pB[10] + pB[11]);
        float a7 = (pB[12] + pB[13]) + (pB[14] + pB[15]);
        lrun += ((a0 + a1) + (a2 + a3)) + ((a4 + a5) + (a6 + a7));

        // pack both halves to bf16 pairs and build 4 P^T B-fragments (16 keys each)
        u32 wA[8], wB[8];
#pragma unroll
        for (int k = 0; k < 8; ++k) {
            union { __hip_bfloat162 h2; u32 u; } cv;
            cv.h2 = __float22bfloat162_rn(float2{pA[2 * k], pA[2 * k + 1]});
            wA[k] = cv.u;
            union { __hip_bfloat162 h2; u32 u; } cw;
            cw.h2 = __float22bfloat162_rn(float2{pB[2 * k], pB[2 * k + 1]});
            wB[k] = cw.u;
        }
        u32 yA0 = __shfl_xor(hi ? wA[0] : wA[2], 32, 64);
        u32 yA1 = __shfl_xor(hi ? wA[1] : wA[3], 32, 64);
        u32 yA2 = __shfl_xor(hi ? wA[4] : wA[6], 32, 64);
        u32 yA3 = __shfl_xor(hi ? wA[5] : wA[7], 32, 64);
        u32 yB0 = __shfl_xor(hi ? wB[0] : wB[2], 32, 64);
        u32 yB1 = __shfl_xor(hi ? wB[1] : wB[3], 32, 64);
        u32 yB2 = __shfl_xor(hi ? wB[4] : wB[6], 32, 64);
        u32 yB3 = __shfl_xor(hi ? wB[5] : wB[7], 32, 64);

        union { u32 u[4]; bf16x8 v; } fr[4];
        fr[0].u[0] = hi ? yA0 : wA[0];
        fr[0].u[1] = hi ? yA1 : wA[1];
        fr[0].u[2] = hi ? wA[2] : yA0;
        fr[0].u[3] = hi ? wA[3] : yA1;
        fr[1].u[0] = hi ? yA2 : wA[4];
        fr[1].u[1] = hi ? yA3 : wA[5];
        fr[1].u[2] = hi ? wA[6] : yA2;
        fr[1].u[3] = hi ? wA[7] : yA3;
        fr[2].u[0] = hi ? yB0 : wB[0];
        fr[2].u[1] = hi ? yB1 : wB[1];
        fr[2].u[2] = hi ? wB[2] : yB0;
        fr[2].u[3] = hi ? wB[3] : yB1;
        fr[3].u[0] = hi ? yB2 : wB[4];
        fr[3].u[1] = hi ? yB3 : wB[5];
        fr[3].u[2] = hi ? wB[6] : yB2;
        fr[3].u[3] = hi ? wB[7] : yB3;

        // ---- PV: ds_read V fragments (swizzled) + MFMA cluster ----
        const char* vb = bcur + 8192;
        __builtin_amdgcn_s_setprio(1);
#pragma unroll
        for (int dd = 0; dd < 2; ++dd) {
#pragma unroll
            for (int kk = 0; kk < 4; ++kk) {
                int c16r = kk * 2 + (lane >> 5);
                bf16x8 vv = *reinterpret_cast<const bf16x8*>(
                    vb + (dd * 32 + l31) * 128 + ((c16r ^ sx) * 16));
                accO[dd] = __builtin_amdgcn_mfma_f32_32x32x16_bf16(vv, fr[kk].v, accO[dd], 0, 0, 0);
            }
        }
        __builtin_amdgcn_s_setprio(0);

        __syncthreads();          // drains vmcnt (stage complete) + all waves done with bcur
        cur ^= 1;
    }

    // combine per-half sums once
    lrun += __shfl_xor(lrun, 32, 64);

    // epilogue: O^T (d-major in regs) -> LDS [q][d] -> coalesced global store
    typedef bf16 (*ObufT)[32][72];
    ObufT obuf = (ObufT)smem;
    float inv = 1.f / lrun;
#pragma unroll
    for (int dd = 0; dd < 2; ++dd)
#pragma unroll
        for (int r = 0; r < 16; r += 2) {
            int d = dd * 32 + (r & 3) + 8 * (r >> 2) + 4 * (lane >> 5);
            union { __hip_bfloat162 h2; u32 u; } cv;
            cv.h2 = __float22bfloat162_rn(float2{accO[dd][r] * inv, accO[dd][r + 1] * inv});
            *reinterpret_cast<u32*>(&obuf[wave][l31][d]) = cv.u;
        }
    __syncthreads();
    {
        int qr = lane >> 1, hf = lane & 1;
        const bf16* orow = &obuf[wave][qr][hf * 32];
        bf16* gout = Out + ((size_t)b * 4096 + q0 + qr) * 512 + h * 64 + hf * 32;
#pragma unroll
        for (int j = 0; j < 4; ++j) {
            bf16x8 t2 = *reinterpret_cast<const bf16x8*>(orow + j * 8);
            *reinterpret_cast<bf16x8*>(gout + j * 8) = t2;
        }
    }
#undef STAGE_TILE
}

extern "C" void kernel_launch(void* const* d_in, const int* in_sizes, int n_in,
                              void* d_out, int out_size, void* d_ws, size_t ws_size,
                              hipStream_t stream) {
    const float* x      = (const float*)d_in[0];
    const float* q_w    = (const float*)d_in[1];
    const float* q_b    = (const float*)d_in[2];
    const float* kv_w   = (const float*)d_in[3];
    const float* kv_b   = (const float*)d_in[4];
    const float* sr_w   = (const float*)d_in[5];
    const float* sr_b   = (const float*)d_in[6];
    const float* ln_g   = (const float*)d_in[7];
    const float* ln_b   = (const float*)d_in[8];
    const float* proj_w = (const float*)d_in[9];
    const float* proj_b = (const float*)d_in[10];

    char* w = (char*)d_ws;
    bf16* x_bf   = (bf16*)w; w += (size_t)8 * 4096 * 512 * 2;
    bf16* q_bf   = (bf16*)w; w += (size_t)8 * 4096 * 512 * 2;
    bf16* qw_bf  = (bf16*)w; w += (size_t)512 * 512 * 2;
    bf16* kvw_bf = (bf16*)w; w += (size_t)1024 * 512 * 2;
    bf16* srw_bf = (bf16*)w; w += (size_t)512 * 2048 * 2;
    bf16* pjw_bf = (bf16*)w; w += (size_t)512 * 512 * 2;
    float* xsr_f = (float*)w; w += (size_t)8 * 1024 * 512 * 4;
    bf16* xsrb   = (bf16*)w; w += (size_t)8 * 1024 * 512 * 2;
    bf16* k_bf   = (bf16*)w; w += (size_t)8 * 8 * 1024 * 64 * 2;
    bf16* vt_bf  = (bf16*)w; w += (size_t)8 * 8 * 1024 * 64 * 2;
    bf16* ao_bf  = (bf16*)w; w += (size_t)8 * 4096 * 512 * 2;

    cast_k<<<dim3(16384), dim3(256), 0, stream>>>(x, x_bf, 4194304);
    cast_k<<<dim3(256),  dim3(256), 0, stream>>>(q_w, qw_bf, 65536);
    cast_k<<<dim3(512),  dim3(256), 0, stream>>>(kv_w, kvw_bf, 131072);
    cast_k<<<dim3(256),  dim3(256), 0, stream>>>(proj_w, pjw_bf, 65536);
    repack_srw_k<<<dim3(4096), dim3(256), 0, stream>>>(sr_w, srw_bf);

    gemm_k<0><<<dim3(1024), dim3(256), 0, stream>>>(x_bf, qw_bf, q_b, q_bf, nullptr, nullptr, 32768, 512, 512);
    gemm_k<1><<<dim3(256), dim3(256), 0, stream>>>(x_bf, srw_bf, sr_b, nullptr, nullptr, xsr_f, 8192, 512, 2048);
    ln_k<<<dim3(8192), dim3(256), 0, stream>>>(xsr_f, ln_g, ln_b, xsrb);
    gemm_k<2><<<dim3(512), dim3(256), 0, stream>>>(xsrb, kvw_bf, kv_b, k_bf, vt_bf, nullptr, 8192, 1024, 512);
    attn_k<<<dim3(2048), dim3(256), 0, stream>>>(q_bf, k_bf, vt_bf, ao_bf);
    gemm_k<3><<<dim3(1024), dim3(256), 0, stream>>>(ao_bf, pjw_bf, proj_b, nullptr, nullptr, (float*)d_out, 32768, 512, 512);
}

// Round 7
// 289.323 us; speedup vs baseline: 1.5297x; 1.0253x over previous
//
#include <hip/hip_runtime.h>
#include <hip/hip_bf16.h>

typedef __hip_bfloat16 bf16;
typedef __bf16 bf16x8 __attribute__((ext_vector_type(8)));
typedef float f32x4 __attribute__((ext_vector_type(4)));
typedef float f32x16 __attribute__((ext_vector_type(16)));
typedef unsigned int u32;
typedef unsigned int u32x2 __attribute__((ext_vector_type(2)));

typedef const __attribute__((address_space(1))) void GV;
typedef __attribute__((address_space(3))) void LV;

#define TM 128
#define TN 128
#define TK 64

static __device__ __forceinline__ float fexp2(float x) {
#if __has_builtin(__builtin_amdgcn_exp2f)
    return __builtin_amdgcn_exp2f(x);
#else
    return exp2f(x);
#endif
}

// ---------------- cast fp32 -> bf16 (4 elems/thread) ----------------
__global__ void cast_k(const float* __restrict__ src, bf16* __restrict__ dst, int n4) {
    int i = blockIdx.x * 256 + threadIdx.x;
    if (i >= n4) return;
    float4 a = reinterpret_cast<const float4*>(src)[i];
    bf16* d = dst + (size_t)i * 4;
    d[0] = __float2bfloat16(a.x);
    d[1] = __float2bfloat16(a.y);
    d[2] = __float2bfloat16(a.z);
    d[3] = __float2bfloat16(a.w);
}

// ---------------- repack sr_w [co][ci][kh][kw] -> [co][p*512+ci] bf16 ----------------
__global__ void repack_srw_k(const float* __restrict__ srw, bf16* __restrict__ dst) {
    int idx = blockIdx.x * 256 + threadIdx.x;   // 512*2048 = 1<<20
    int co = idx >> 11;
    int t  = idx & 2047;
    int p  = t >> 9;        // kh*2+kw
    int ci = t & 511;
    dst[idx] = __float2bfloat16(srw[(size_t)co * 2048 + ci * 4 + p]);
}

// ---------------- generic bf16 GEMM, m97 structure ----------------
template<int KIND>
__launch_bounds__(256)
__global__ void gemm_k(const bf16* __restrict__ A, const bf16* __restrict__ Bw,
                       const float* __restrict__ bias,
                       bf16* __restrict__ outB, bf16* __restrict__ outB2,
                       float* __restrict__ outF,
                       int M, int N, int K) {
    __shared__ __align__(16) bf16 ldsA[TM * TK];
    __shared__ __align__(16) bf16 ldsB[TN * TK];
    const int tid = threadIdx.x;
    const int lane = tid & 63;
    const int wave = tid >> 6;
    const int ntn = N / TN;
    const int row0 = (blockIdx.x / ntn) * TM;
    const int col0 = (blockIdx.x % ntn) * TN;
    const int wm = wave >> 1, wn = wave & 1;

    f32x4 acc[4][4];
#pragma unroll
    for (int i = 0; i < 4; ++i)
#pragma unroll
        for (int j = 0; j < 4; ++j) acc[i][j] = f32x4{0.f, 0.f, 0.f, 0.f};

    for (int k0 = 0; k0 < K; k0 += TK) {
#pragma unroll
        for (int t = 0; t < 4; ++t) {
            int idx = t * 256 + tid;
            int r = idx >> 3;
            int c = (idx & 7) * 8;
            const bf16* src;
            if (KIND == 1) {
                int rr = row0 + r;
                int k = k0 + c;
                int p = k >> 9, ci = k & 511;
                int b = rr >> 10, ii = (rr >> 5) & 31, jj = rr & 31;
                int n_in = (2 * ii + (p >> 1)) * 64 + 2 * jj + (p & 1);
                src = A + ((size_t)(b * 4096 + n_in)) * 512 + ci;
            } else {
                src = A + (size_t)(row0 + r) * K + k0 + c;
            }
            __builtin_amdgcn_global_load_lds((GV*)src, (LV*)&ldsA[idx * 8], 16, 0, 0);
        }
#pragma unroll
        for (int t = 0; t < 4; ++t) {
            int idx = t * 256 + tid;
            int r = idx >> 3;
            int c = (idx & 7) * 8;
            const bf16* src = Bw + (size_t)(col0 + r) * K + k0 + c;
            __builtin_amdgcn_global_load_lds((GV*)src, (LV*)&ldsB[idx * 8], 16, 0, 0);
        }
        __syncthreads();
#pragma unroll
        for (int kk = 0; kk < 2; ++kk) {
            const int kb = kk * 32 + (lane >> 4) * 8;
            bf16x8 af[4], bfr[4];
#pragma unroll
            for (int m = 0; m < 4; ++m)
                af[m] = *reinterpret_cast<const bf16x8*>(&ldsA[(wm * 64 + m * 16 + (lane & 15)) * TK + kb]);
#pragma unroll
            for (int n = 0; n < 4; ++n)
                bfr[n] = *reinterpret_cast<const bf16x8*>(&ldsB[(wn * 64 + n * 16 + (lane & 15)) * TK + kb]);
#pragma unroll
            for (int m = 0; m < 4; ++m)
#pragma unroll
                for (int n = 0; n < 4; ++n)
                    acc[m][n] = __builtin_amdgcn_mfma_f32_16x16x32_bf16(af[m], bfr[n], acc[m][n], 0, 0, 0);
        }
        __syncthreads();
    }

#pragma unroll
    for (int m = 0; m < 4; ++m) {
#pragma unroll
        for (int n = 0; n < 4; ++n) {
#pragma unroll
            for (int r = 0; r < 4; ++r) {
                int grow = row0 + wm * 64 + m * 16 + (lane >> 4) * 4 + r;
                int gcol = col0 + wn * 64 + n * 16 + (lane & 15);
                float v = acc[m][n][r] + bias[gcol];
                if (KIND == 0) {
                    int b = grow >> 12, nn = grow & 4095;
                    int h = gcol >> 6, dd = gcol & 63;
                    // scale = 1/8 * log2(e): softmax computed in exp2 domain
                    outB[(((size_t)(b * 8 + h)) * 4096 + nn) * 64 + dd] =
                        __float2bfloat16(v * 0.18033688011112042f);
                } else if (KIND == 1) {
                    outF[(size_t)grow * 512 + gcol] = v;
                } else if (KIND == 2) {
                    int b = grow >> 10, mm = grow & 1023;
                    if (gcol < 512) {
                        int h = gcol >> 6, dd = gcol & 63;
                        outB[(((size_t)(b * 8 + h)) * 1024 + mm) * 64 + dd] = __float2bfloat16(v);
                    } else {
                        int c2 = gcol - 512;
                        int h = c2 >> 6, dd = c2 & 63;
                        outB2[(((size_t)(b * 8 + h)) * 64 + dd) * 1024 + mm] = __float2bfloat16(v);
                    }
                } else {
                    outF[(size_t)grow * 512 + gcol] = v;
                }
            }
        }
    }
}

// ---------------- layernorm (fp32 in -> bf16 out), one block per row ----------------
__global__ void ln_k(const float* __restrict__ xsr, const float* __restrict__ g,
                     const float* __restrict__ bta, bf16* __restrict__ out) {
    const int row = blockIdx.x;
    const int tid = threadIdx.x;          // 256
    const float* xr = xsr + (size_t)row * 512;
    float2 v = *reinterpret_cast<const float2*>(xr + tid * 2);
    float s = v.x + v.y;
    float sq = v.x * v.x + v.y * v.y;
#pragma unroll
    for (int m = 1; m < 64; m <<= 1) {
        s += __shfl_xor(s, m, 64);
        sq += __shfl_xor(sq, m, 64);
    }
    __shared__ float rs[4], rq[4];
    int wave = tid >> 6, lane = tid & 63;
    if (lane == 0) { rs[wave] = s; rq[wave] = sq; }
    __syncthreads();
    s = rs[0] + rs[1] + rs[2] + rs[3];
    sq = rq[0] + rq[1] + rq[2] + rq[3];
    float mu = s * (1.f / 512.f);
    float var = sq * (1.f / 512.f) - mu * mu;
    float rstd = rsqrtf(var + 1e-5f);
    bf16* orow = out + (size_t)row * 512;
    orow[tid * 2]     = __float2bfloat16((v.x - mu) * rstd * g[tid * 2] + bta[tid * 2]);
    orow[tid * 2 + 1] = __float2bfloat16((v.y - mu) * rstd * g[tid * 2 + 1] + bta[tid * 2 + 1]);
}

// ---------------- flash attention v7: fragment-major LDS (conflict-free) + permlane ----------------
// Q: [bh][n][64] (pre-scaled by 1/8*log2e), K: [bh][m][64], Vt: [bh][64][m], Out: [b][n][512]
// K-tile in LDS as [c][key][half], V-tile as [kk][d][half]: every ds_read_b128 has the
// wave's 64 lanes covering one contiguous 1024B block -> zero bank conflicts, and all
// read addrs = one base VGPR + immediate offset. P-exchange via permlane32_swap (no LDS).
__launch_bounds__(256, 2)
__global__ void attn_k(const bf16* __restrict__ Q, const bf16* __restrict__ Kb,
                       const bf16* __restrict__ Vt, bf16* __restrict__ Out) {
    const int p = blockIdx.x;                  // 2048 blocks
    const int bh = (p & 7) * 8 + (p >> 8);     // XCD-pinned
    const int qb = (p >> 3) & 31;
    const int b = bh >> 3, h = bh & 7;
    const int tid = threadIdx.x, lane = tid & 63, wave = tid >> 6;
    const int q0 = qb * 128 + wave * 32;
    const int l31 = lane & 31;
    const int klo8 = (lane >> 5) * 8;

    const bf16* Qp = Q + ((size_t)bh * 4096 + q0) * 64;
    const bf16* Kp = Kb + (size_t)bh * 1024 * 64;
    const bf16* Vp = Vt + (size_t)bh * 64 * 1024;

    // smem: two 16 KB buffers; each = K-tile (8 KB, [c][key][half]) + V-tile (8 KB, [kk][d][half]).
    __shared__ __align__(16) char smem[32768];

    // Q fragments (B-operand of swapped QK^T): col=query=l31, k=d contiguous
    bf16x8 qf[4];
#pragma unroll
    for (int c = 0; c < 4; ++c)
        qf[c] = *reinterpret_cast<const bf16x8*>(Qp + (size_t)l31 * 64 + c * 16 + klo8);

    f32x16 accO[2];
    accO[0] = f32x16{};
    accO[1] = f32x16{};
    float mrun = -1e30f;
    float lrun = 0.f;                 // per half-lane; combined after the loop

    // staging helpers: wave w stages plane c=w (K) / kk=w (V); two 64-chunk instrs each.
    const int l2 = lane >> 1;          // key-or-d index within half-tile
    const int lh8 = (lane & 1) * 8;    // element offset within 16-elem chunk
    const int w16 = wave * 16;

    // per-lane read base (compile-time offsets added per fragment)
    const char* rb = smem + l31 * 32 + (lane >> 5) * 16;

#define STAGE_TILE(KT, BASE)                                                              \
    do {                                                                                  \
        char* _b = (BASE);                                                                \
        __builtin_amdgcn_global_load_lds((GV*)(Kp + (size_t)((KT) + l2) * 64 + w16 + lh8),\
                                         (LV*)(_b + wave * 2048), 16, 0, 0);              \
        __builtin_amdgcn_global_load_lds((GV*)(Kp + (size_t)((KT) + 32 + l2) * 64 + w16 + lh8),\
                                         (LV*)(_b + wave * 2048 + 1024), 16, 0, 0);       \
        __builtin_amdgcn_global_load_lds((GV*)(Vp + (size_t)l2 * 1024 + (KT) + w16 + lh8),\
                                         (LV*)(_b + 8192 + wave * 2048), 16, 0, 0);       \
        __builtin_amdgcn_global_load_lds((GV*)(Vp + (size_t)(32 + l2) * 1024 + (KT) + w16 + lh8),\
                                         (LV*)(_b + 8192 + wave * 2048 + 1024), 16, 0, 0);\
    } while (0)

    // prologue: stage tile 0
    STAGE_TILE(0, smem);
    __syncthreads();

    int cur = 0;
    for (int t = 0; t < 16; ++t) {
        const char* rc = rb + cur * 16384;
        if (t < 15) STAGE_TILE((t + 1) * 64, smem + (cur ^ 1) * 16384);

        // ---- ds_read K fragments (conflict-free, base+imm) + QK^T for both halves ----
        bf16x8 kf0[4], kf1[4];
#pragma unroll
        for (int c = 0; c < 4; ++c) {
            kf0[c] = *reinterpret_cast<const bf16x8*>(rc + c * 2048);
            kf1[c] = *reinterpret_cast<const bf16x8*>(rc + c * 2048 + 1024);
        }
        f32x16 sA = f32x16{}, sB = f32x16{};
#pragma unroll
        for (int c = 0; c < 4; ++c) {
            sA = __builtin_amdgcn_mfma_f32_32x32x16_bf16(kf0[c], qf[c], sA, 0, 0, 0);
            sB = __builtin_amdgcn_mfma_f32_32x32x16_bf16(kf1[c], qf[c], sB, 0, 0, 0);
        }

        // ---- softmax over 64 keys (log2 domain) ----
        float m0 = fmaxf(fmaxf(sA[0], sA[1]), fmaxf(sA[2], sA[3]));
        float m1 = fmaxf(fmaxf(sA[4], sA[5]), fmaxf(sA[6], sA[7]));
        float m2 = fmaxf(fmaxf(sA[8], sA[9]), fmaxf(sA[10], sA[11]));
        float m3 = fmaxf(fmaxf(sA[12], sA[13]), fmaxf(sA[14], sA[15]));
        float m4 = fmaxf(fmaxf(sB[0], sB[1]), fmaxf(sB[2], sB[3]));
        float m5 = fmaxf(fmaxf(sB[4], sB[5]), fmaxf(sB[6], sB[7]));
        float m6 = fmaxf(fmaxf(sB[8], sB[9]), fmaxf(sB[10], sB[11]));
        float m7 = fmaxf(fmaxf(sB[12], sB[13]), fmaxf(sB[14], sB[15]));
        float mt = fmaxf(fmaxf(fmaxf(m0, m1), fmaxf(m2, m3)),
                         fmaxf(fmaxf(m4, m5), fmaxf(m6, m7)));
        {   // cross-half max via permlane32_swap (no LDS)
            u32 mu = __builtin_bit_cast(u32, mt);
            u32x2 mm = __builtin_amdgcn_permlane32_swap(mu, mu, false, false);
            mt = fmaxf(__builtin_bit_cast(float, mm[0]), __builtin_bit_cast(float, mm[1]));
        }

        if (!__all(mt - mrun <= 8.f)) {
            float mn = fmaxf(mrun, mt);
            float fac = fexp2(mrun - mn);
            lrun *= fac;
#pragma unroll
            for (int dd = 0; dd < 2; ++dd)
#pragma unroll
                for (int r = 0; r < 16; ++r) accO[dd][r] *= fac;
            mrun = mn;
        }

        float pA[16], pB[16];
#pragma unroll
        for (int r = 0; r < 16; ++r) pA[r] = fexp2(sA[r] - mrun);
#pragma unroll
        for (int r = 0; r < 16; ++r) pB[r] = fexp2(sB[r] - mrun);
        float a0 = (pA[0] + pA[1]) + (pA[2] + pA[3]);
        float a1 = (pA[4] + pA[5]) + (pA[6] + pA[7]);
        float a2 = (pA[8] + pA[9]) + (pA[10] + pA[11]);
        float a3 = (pA[12] + pA[13]) + (pA[14] + pA[15]);
        float a4 = (pB[0] + pB[1]) + (pB[2] + pB[3]);
        float a5 = (pB[4] + pB[5]) + (pB[6] + pB[7]);
        float a6 = (pB[8] + pB[9]) + (pB[10] + pB[11]);
        float a7 = (pB[12] + pB[13]) + (pB[14] + pB[15]);
        lrun += ((a0 + a1) + (a2 + a3)) + ((a4 + a5) + (a6 + a7));

        // pack to bf16 pairs
        u32 wA[8], wB[8];
#pragma unroll
        for (int k = 0; k < 8; ++k) {
            union { __hip_bfloat162 h2; u32 u; } cv;
            cv.h2 = __float22bfloat162_rn(float2{pA[2 * k], pA[2 * k + 1]});
            wA[k] = cv.u;
            union { __hip_bfloat162 h2; u32 u; } cw;
            cw.h2 = __float22bfloat162_rn(float2{pB[2 * k], pB[2 * k + 1]});
            wB[k] = cw.u;
        }
        // P^T B-fragments via permlane32_swap: swap(w0,w2) -> (u0 lo/hi, u2 lo/hi) etc.
        union { u32 u[4]; bf16x8 v; } fr[4];
        {
            u32x2 e0 = __builtin_amdgcn_permlane32_swap(wA[0], wA[2], false, false);
            u32x2 e1 = __builtin_amdgcn_permlane32_swap(wA[1], wA[3], false, false);
            fr[0].u[0] = e0[0]; fr[0].u[1] = e1[0]; fr[0].u[2] = e0[1]; fr[0].u[3] = e1[1];
            u32x2 e2 = __builtin_amdgcn_permlane32_swap(wA[4], wA[6], false, false);
            u32x2 e3 = __builtin_amdgcn_permlane32_swap(wA[5], wA[7], false, false);
            fr[1].u[0] = e2[0]; fr[1].u[1] = e3[0]; fr[1].u[2] = e2[1]; fr[1].u[3] = e3[1];
            u32x2 e4 = __builtin_amdgcn_permlane32_swap(wB[0], wB[2], false, false);
            u32x2 e5 = __builtin_amdgcn_permlane32_swap(wB[1], wB[3], false, false);
            fr[2].u[0] = e4[0]; fr[2].u[1] = e5[0]; fr[2].u[2] = e4[1]; fr[2].u[3] = e5[1];
            u32x2 e6 = __builtin_amdgcn_permlane32_swap(wB[4], wB[6], false, false);
            u32x2 e7 = __builtin_amdgcn_permlane32_swap(wB[5], wB[7], false, false);
            fr[3].u[0] = e6[0]; fr[3].u[1] = e7[0]; fr[3].u[2] = e6[1]; fr[3].u[3] = e7[1];
        }

        // ---- PV: ds_read V fragments (conflict-free) + MFMA cluster ----
        __builtin_amdgcn_s_setprio(1);
#pragma unroll
        for (int dd = 0; dd < 2; ++dd) {
#pragma unroll
            for (int kk = 0; kk < 4; ++kk) {
                bf16x8 vv = *reinterpret_cast<const bf16x8*>(rc + 8192 + kk * 2048 + dd * 1024);
                accO[dd] = __builtin_amdgcn_mfma_f32_32x32x16_bf16(vv, fr[kk].v, accO[dd], 0, 0, 0);
            }
        }
        __builtin_amdgcn_s_setprio(0);

        __syncthreads();          // drains vmcnt (stage complete) + all waves done with bcur
        cur ^= 1;
    }

    // combine per-half sums once (permlane, no LDS)
    {
        u32 lu = __builtin_bit_cast(u32, lrun);
        u32x2 ll = __builtin_amdgcn_permlane32_swap(lu, lu, false, false);
        lrun = __builtin_bit_cast(float, ll[0]) + __builtin_bit_cast(float, ll[1]);
    }

    // epilogue: O^T (d-major in regs) -> LDS [q][d] -> coalesced global store
    typedef bf16 (*ObufT)[32][72];
    ObufT obuf = (ObufT)smem;
    float inv = 1.f / lrun;
#pragma unroll
    for (int dd = 0; dd < 2; ++dd)
#pragma unroll
        for (int r = 0; r < 16; r += 2) {
            int d = dd * 32 + (r & 3) + 8 * (r >> 2) + 4 * (lane >> 5);
            union { __hip_bfloat162 h2; u32 u; } cv;
            cv.h2 = __float22bfloat162_rn(float2{accO[dd][r] * inv, accO[dd][r + 1] * inv});
            *reinterpret_cast<u32*>(&obuf[wave][l31][d]) = cv.u;
        }
    __syncthreads();
    {
        int qr = lane >> 1, hf = lane & 1;
        const bf16* orow = &obuf[wave][qr][hf * 32];
        bf16* gout = Out + ((size_t)b * 4096 + q0 + qr) * 512 + h * 64 + hf * 32;
#pragma unroll
        for (int j = 0; j < 4; ++j) {
            bf16x8 t2 = *reinterpret_cast<const bf16x8*>(orow + j * 8);
            *reinterpret_cast<bf16x8*>(gout + j * 8) = t2;
        }
    }
#undef STAGE_TILE
}

extern "C" void kernel_launch(void* const* d_in, const int* in_sizes, int n_in,
                              void* d_out, int out_size, void* d_ws, size_t ws_size,
                              hipStream_t stream) {
    const float* x      = (const float*)d_in[0];
    const float* q_w    = (const float*)d_in[1];
    const float* q_b    = (const float*)d_in[2];
    const float* kv_w   = (const float*)d_in[3];
    const float* kv_b   = (const float*)d_in[4];
    const float* sr_w   = (const float*)d_in[5];
    const float* sr_b   = (const float*)d_in[6];
    const float* ln_g   = (const float*)d_in[7];
    const float* ln_b   = (const float*)d_in[8];
    const float* proj_w = (const float*)d_in[9];
    const float* proj_b = (const float*)d_in[10];

    char* w = (char*)d_ws;
    bf16* x_bf   = (bf16*)w; w += (size_t)8 * 4096 * 512 * 2;
    bf16* q_bf   = (bf16*)w; w += (size_t)8 * 4096 * 512 * 2;
    bf16* qw_bf  = (bf16*)w; w += (size_t)512 * 512 * 2;
    bf16* kvw_bf = (bf16*)w; w += (size_t)1024 * 512 * 2;
    bf16* srw_bf = (bf16*)w; w += (size_t)512 * 2048 * 2;
    bf16* pjw_bf = (bf16*)w; w += (size_t)512 * 512 * 2;
    float* xsr_f = (float*)w; w += (size_t)8 * 1024 * 512 * 4;
    bf16* xsrb   = (bf16*)w; w += (size_t)8 * 1024 * 512 * 2;
    bf16* k_bf   = (bf16*)w; w += (size_t)8 * 8 * 1024 * 64 * 2;
    bf16* vt_bf  = (bf16*)w; w += (size_t)8 * 8 * 1024 * 64 * 2;
    bf16* ao_bf  = (bf16*)w; w += (size_t)8 * 4096 * 512 * 2;

    cast_k<<<dim3(16384), dim3(256), 0, stream>>>(x, x_bf, 4194304);
    cast_k<<<dim3(256),  dim3(256), 0, stream>>>(q_w, qw_bf, 65536);
    cast_k<<<dim3(512),  dim3(256), 0, stream>>>(kv_w, kvw_bf, 131072);
    cast_k<<<dim3(256),  dim3(256), 0, stream>>>(proj_w, pjw_bf, 65536);
    repack_srw_k<<<dim3(4096), dim3(256), 0, stream>>>(sr_w, srw_bf);

    gemm_k<0><<<dim3(1024), dim3(256), 0, stream>>>(x_bf, qw_bf, q_b, q_bf, nullptr, nullptr, 32768, 512, 512);
    gemm_k<1><<<dim3(256), dim3(256), 0, stream>>>(x_bf, srw_bf, sr_b, nullptr, nullptr, xsr_f, 8192, 512, 2048);
    ln_k<<<dim3(8192), dim3(256), 0, stream>>>(xsr_f, ln_g, ln_b, xsrb);
    gemm_k<2><<<dim3(512), dim3(256), 0, stream>>>(xsrb, kvw_bf, kv_b, k_bf, vt_bf, nullptr, 8192, 1024, 512);
    attn_k<<<dim3(2048), dim3(256), 0, stream>>>(q_bf, k_bf, vt_bf, ao_bf);
    gemm_k<3><<<dim3(1024), dim3(256), 0, stream>>>(ao_bf, pjw_bf, proj_b, nullptr, nullptr, (float*)d_out, 32768, 512, 512);
}

// Round 8
// 280.807 us; speedup vs baseline: 1.5761x; 1.0303x over previous
//
#include <hip/hip_runtime.h>
#include <hip/hip_bf16.h>

typedef __hip_bfloat16 bf16;
typedef __bf16 bf16x8 __attribute__((ext_vector_type(8)));
typedef float f32x4 __attribute__((ext_vector_type(4)));
typedef float f32x16 __attribute__((ext_vector_type(16)));
typedef unsigned int u32;
typedef unsigned int u32x2 __attribute__((ext_vector_type(2)));

typedef const __attribute__((address_space(1))) void GV;
typedef __attribute__((address_space(3))) void LV;

#define TM 128
#define TN 128
#define TK 64

static __device__ __forceinline__ float fexp2(float x) {
#if __has_builtin(__builtin_amdgcn_exp2f)
    return __builtin_amdgcn_exp2f(x);
#else
    return exp2f(x);
#endif
}

// ---------------- cast fp32 -> bf16 (4 elems/thread) ----------------
__global__ void cast_k(const float* __restrict__ src, bf16* __restrict__ dst, int n4) {
    int i = blockIdx.x * 256 + threadIdx.x;
    if (i >= n4) return;
    float4 a = reinterpret_cast<const float4*>(src)[i];
    bf16* d = dst + (size_t)i * 4;
    d[0] = __float2bfloat16(a.x);
    d[1] = __float2bfloat16(a.y);
    d[2] = __float2bfloat16(a.z);
    d[3] = __float2bfloat16(a.w);
}

// ---------------- repack sr_w [co][ci][kh][kw] -> [co][p*512+ci] bf16 ----------------
__global__ void repack_srw_k(const float* __restrict__ srw, bf16* __restrict__ dst) {
    int idx = blockIdx.x * 256 + threadIdx.x;   // 512*2048 = 1<<20
    int co = idx >> 11;
    int t  = idx & 2047;
    int p  = t >> 9;        // kh*2+kw
    int ci = t & 511;
    dst[idx] = __float2bfloat16(srw[(size_t)co * 2048 + ci * 4 + p]);
}

// ---------------- generic bf16 GEMM, double-buffered + counted vmcnt (T4) ----------------
template<int KIND>
__launch_bounds__(256)
__global__ void gemm_k(const bf16* __restrict__ A, const bf16* __restrict__ Bw,
                       const float* __restrict__ bias,
                       bf16* __restrict__ outB, bf16* __restrict__ outB2,
                       float* __restrict__ outF,
                       int M, int N, int K) {
    __shared__ __align__(16) bf16 ldsA[2][TM * TK];
    __shared__ __align__(16) bf16 ldsB[2][TM * TK];
    const int tid = threadIdx.x;
    const int lane = tid & 63;
    const int wave = tid >> 6;
    const int ntn = N / TN;
    const int row0 = (blockIdx.x / ntn) * TM;
    const int col0 = (blockIdx.x % ntn) * TN;
    const int wm = wave >> 1, wn = wave & 1;
    const int NK = K / TK;

    f32x4 acc[4][4];
#pragma unroll
    for (int i = 0; i < 4; ++i)
#pragma unroll
        for (int j = 0; j < 4; ++j) acc[i][j] = f32x4{0.f, 0.f, 0.f, 0.f};

    // stage K-step ks into buffer buf (8 global_load_lds per thread)
    auto stage = [&](int ks, int buf) {
        const int k0 = ks * TK;
#pragma unroll
        for (int t = 0; t < 4; ++t) {
            int idx = t * 256 + tid;
            int r = idx >> 3;
            int c = (idx & 7) * 8;
            const bf16* src;
            if (KIND == 1) {
                int rr = row0 + r;
                int k = k0 + c;
                int p = k >> 9, ci = k & 511;
                int b = rr >> 10, ii = (rr >> 5) & 31, jj = rr & 31;
                int n_in = (2 * ii + (p >> 1)) * 64 + 2 * jj + (p & 1);
                src = A + ((size_t)(b * 4096 + n_in)) * 512 + ci;
            } else {
                src = A + (size_t)(row0 + r) * K + k0 + c;
            }
            __builtin_amdgcn_global_load_lds((GV*)src, (LV*)&ldsA[buf][idx * 8], 16, 0, 0);
        }
#pragma unroll
        for (int t = 0; t < 4; ++t) {
            int idx = t * 256 + tid;
            int r = idx >> 3;
            int c = (idx & 7) * 8;
            const bf16* src = Bw + (size_t)(col0 + r) * K + k0 + c;
            __builtin_amdgcn_global_load_lds((GV*)src, (LV*)&ldsB[buf][idx * 8], 16, 0, 0);
        }
    };

    stage(0, 0);
    stage(1, 1);

    int cur = 0;
    for (int ks = 0; ks < NK; ++ks) {
        // wait for tile-ks loads (issued 2 iters ago); keep next tile's 8 in flight
        if (ks < NK - 1) asm volatile("s_waitcnt vmcnt(8)" ::: "memory");
        else             asm volatile("s_waitcnt vmcnt(0)" ::: "memory");
        __builtin_amdgcn_s_barrier();

#pragma unroll
        for (int kk = 0; kk < 2; ++kk) {
            const int kb = kk * 32 + (lane >> 4) * 8;
            bf16x8 af[4], bfr[4];
#pragma unroll
            for (int m = 0; m < 4; ++m)
                af[m] = *reinterpret_cast<const bf16x8*>(&ldsA[cur][(wm * 64 + m * 16 + (lane & 15)) * TK + kb]);
#pragma unroll
            for (int n = 0; n < 4; ++n)
                bfr[n] = *reinterpret_cast<const bf16x8*>(&ldsB[cur][(wn * 64 + n * 16 + (lane & 15)) * TK + kb]);
#pragma unroll
            for (int m = 0; m < 4; ++m)
#pragma unroll
                for (int n = 0; n < 4; ++n)
                    acc[m][n] = __builtin_amdgcn_mfma_f32_16x16x32_bf16(af[m], bfr[n], acc[m][n], 0, 0, 0);
        }

        __builtin_amdgcn_s_barrier();
        if (ks + 2 < NK) stage(ks + 2, cur);
        cur ^= 1;
    }

#pragma unroll
    for (int m = 0; m < 4; ++m) {
#pragma unroll
        for (int n = 0; n < 4; ++n) {
#pragma unroll
            for (int r = 0; r < 4; ++r) {
                int grow = row0 + wm * 64 + m * 16 + (lane >> 4) * 4 + r;
                int gcol = col0 + wn * 64 + n * 16 + (lane & 15);
                float v = acc[m][n][r] + bias[gcol];
                if (KIND == 0) {
                    int b = grow >> 12, nn = grow & 4095;
                    int h = gcol >> 6, dd = gcol & 63;
                    // scale = 1/8 * log2(e): softmax computed in exp2 domain
                    outB[(((size_t)(b * 8 + h)) * 4096 + nn) * 64 + dd] =
                        __float2bfloat16(v * 0.18033688011112042f);
                } else if (KIND == 1) {
                    outF[(size_t)grow * 512 + gcol] = v;
                } else if (KIND == 2) {
                    int b = grow >> 10, mm = grow & 1023;
                    if (gcol < 512) {
                        int h = gcol >> 6, dd = gcol & 63;
                        outB[(((size_t)(b * 8 + h)) * 1024 + mm) * 64 + dd] = __float2bfloat16(v);
                    } else {
                        int c2 = gcol - 512;
                        int h = c2 >> 6, dd = c2 & 63;
                        outB2[(((size_t)(b * 8 + h)) * 64 + dd) * 1024 + mm] = __float2bfloat16(v);
                    }
                } else {
                    outF[(size_t)grow * 512 + gcol] = v;
                }
            }
        }
    }
}

// ---------------- layernorm (fp32 in -> bf16 out), one block per row ----------------
__global__ void ln_k(const float* __restrict__ xsr, const float* __restrict__ g,
                     const float* __restrict__ bta, bf16* __restrict__ out) {
    const int row = blockIdx.x;
    const int tid = threadIdx.x;          // 256
    const float* xr = xsr + (size_t)row * 512;
    float2 v = *reinterpret_cast<const float2*>(xr + tid * 2);
    float s = v.x + v.y;
    float sq = v.x * v.x + v.y * v.y;
#pragma unroll
    for (int m = 1; m < 64; m <<= 1) {
        s += __shfl_xor(s, m, 64);
        sq += __shfl_xor(sq, m, 64);
    }
    __shared__ float rs[4], rq[4];
    int wave = tid >> 6, lane = tid & 63;
    if (lane == 0) { rs[wave] = s; rq[wave] = sq; }
    __syncthreads();
    s = rs[0] + rs[1] + rs[2] + rs[3];
    sq = rq[0] + rq[1] + rq[2] + rq[3];
    float mu = s * (1.f / 512.f);
    float var = sq * (1.f / 512.f) - mu * mu;
    float rstd = rsqrtf(var + 1e-5f);
    bf16* orow = out + (size_t)row * 512;
    orow[tid * 2]     = __float2bfloat16((v.x - mu) * rstd * g[tid * 2] + bta[tid * 2]);
    orow[tid * 2 + 1] = __float2bfloat16((v.y - mu) * rstd * g[tid * 2 + 1] + bta[tid * 2 + 1]);
}

// ---------------- flash attention v8: counted-vmcnt pipeline, raw barriers ----------------
// Q: [bh][n][64] (pre-scaled by 1/8*log2e), K: [bh][m][64], Vt: [bh][64][m], Out: [b][n][512]
__launch_bounds__(256, 2)
__global__ void attn_k(const bf16* __restrict__ Q, const bf16* __restrict__ Kb,
                       const bf16* __restrict__ Vt, bf16* __restrict__ Out) {
    const int p = blockIdx.x;                  // 2048 blocks
    const int bh = (p & 7) * 8 + (p >> 8);     // XCD-pinned
    const int qb = (p >> 3) & 31;
    const int b = bh >> 3, h = bh & 7;
    const int tid = threadIdx.x, lane = tid & 63, wave = tid >> 6;
    const int q0 = qb * 128 + wave * 32;
    const int l31 = lane & 31;
    const int klo8 = (lane >> 5) * 8;

    const bf16* Qp = Q + ((size_t)bh * 4096 + q0) * 64;
    const bf16* Kp = Kb + (size_t)bh * 1024 * 64;
    const bf16* Vp = Vt + (size_t)bh * 64 * 1024;

    // smem: two 16 KB buffers; each = K-tile (8 KB, [c][key][half]) + V-tile (8 KB, [kk][d][half]).
    __shared__ __align__(16) char smem[32768];

    // Q fragments (B-operand of swapped QK^T): col=query=l31, k=d contiguous
    bf16x8 qf[4];
#pragma unroll
    for (int c = 0; c < 4; ++c)
        qf[c] = *reinterpret_cast<const bf16x8*>(Qp + (size_t)l31 * 64 + c * 16 + klo8);

    f32x16 accO[2];
    accO[0] = f32x16{};
    accO[1] = f32x16{};
    float mrun = -1e30f;
    float lrun = 0.f;                 // per half-lane; combined after the loop
    const f32x16 z16 = f32x16{};      // loop-invariant zero C-operand

    // staging helpers: wave w stages plane c=w (K) / kk=w (V).
    const int l2 = lane >> 1;          // key-or-d index within half-tile
    const int lh8 = (lane & 1) * 8;    // element offset within 16-elem chunk
    const int w16 = wave * 16;

    // per-lane read base (compile-time offsets added per fragment)
    const char* rb = smem + l31 * 32 + (lane >> 5) * 16;

#define STAGE_TILE(KT, BASE)                                                              \
    do {                                                                                  \
        char* _b = (BASE);                                                                \
        __builtin_amdgcn_global_load_lds((GV*)(Kp + (size_t)((KT) + l2) * 64 + w16 + lh8),\
                                         (LV*)(_b + wave * 2048), 16, 0, 0);              \
        __builtin_amdgcn_global_load_lds((GV*)(Kp + (size_t)((KT) + 32 + l2) * 64 + w16 + lh8),\
                                         (LV*)(_b + wave * 2048 + 1024), 16, 0, 0);       \
        __builtin_amdgcn_global_load_lds((GV*)(Vp + (size_t)l2 * 1024 + (KT) + w16 + lh8),\
                                         (LV*)(_b + 8192 + wave * 2048), 16, 0, 0);       \
        __builtin_amdgcn_global_load_lds((GV*)(Vp + (size_t)(32 + l2) * 1024 + (KT) + w16 + lh8),\
                                         (LV*)(_b + 8192 + wave * 2048 + 1024), 16, 0, 0);\
    } while (0)

    // prologue: stage tiles 0 and 1 (8 loads/lane in flight)
    STAGE_TILE(0, smem);
    STAGE_TILE(64, smem + 16384);

    int cur = 0;
    for (int t = 0; t < 16; ++t) {
        // wait for tile-t loads (keep tile-t+1's 4 in flight), then sync all waves
        if (t < 15) asm volatile("s_waitcnt vmcnt(4)" ::: "memory");
        else        asm volatile("s_waitcnt vmcnt(0)" ::: "memory");
        __builtin_amdgcn_s_barrier();

        const char* rc = rb + cur * 16384;

        // ---- ds_read K fragments (conflict-free, base+imm) + QK^T for both halves ----
        bf16x8 kf0[4], kf1[4];
#pragma unroll
        for (int c = 0; c < 4; ++c) {
            kf0[c] = *reinterpret_cast<const bf16x8*>(rc + c * 2048);
            kf1[c] = *reinterpret_cast<const bf16x8*>(rc + c * 2048 + 1024);
        }
        f32x16 sA = __builtin_amdgcn_mfma_f32_32x32x16_bf16(kf0[0], qf[0], z16, 0, 0, 0);
        f32x16 sB = __builtin_amdgcn_mfma_f32_32x32x16_bf16(kf1[0], qf[0], z16, 0, 0, 0);
#pragma unroll
        for (int c = 1; c < 4; ++c) {
            sA = __builtin_amdgcn_mfma_f32_32x32x16_bf16(kf0[c], qf[c], sA, 0, 0, 0);
            sB = __builtin_amdgcn_mfma_f32_32x32x16_bf16(kf1[c], qf[c], sB, 0, 0, 0);
        }

        // ---- softmax over 64 keys (log2 domain) ----
        float m0 = fmaxf(fmaxf(sA[0], sA[1]), fmaxf(sA[2], sA[3]));
        float m1 = fmaxf(fmaxf(sA[4], sA[5]), fmaxf(sA[6], sA[7]));
        float m2 = fmaxf(fmaxf(sA[8], sA[9]), fmaxf(sA[10], sA[11]));
        float m3 = fmaxf(fmaxf(sA[12], sA[13]), fmaxf(sA[14], sA[15]));
        float m4 = fmaxf(fmaxf(sB[0], sB[1]), fmaxf(sB[2], sB[3]));
        float m5 = fmaxf(fmaxf(sB[4], sB[5]), fmaxf(sB[6], sB[7]));
        float m6 = fmaxf(fmaxf(sB[8], sB[9]), fmaxf(sB[10], sB[11]));
        float m7 = fmaxf(fmaxf(sB[12], sB[13]), fmaxf(sB[14], sB[15]));
        float mt = fmaxf(fmaxf(fmaxf(m0, m1), fmaxf(m2, m3)),
                         fmaxf(fmaxf(m4, m5), fmaxf(m6, m7)));
        {   // cross-half max via permlane32_swap (no LDS)
            u32 mu = __builtin_bit_cast(u32, mt);
            u32x2 mm = __builtin_amdgcn_permlane32_swap(mu, mu, false, false);
            mt = fmaxf(__builtin_bit_cast(float, mm[0]), __builtin_bit_cast(float, mm[1]));
        }

        if (!__all(mt - mrun <= 8.f)) {
            float mn = fmaxf(mrun, mt);
            float fac = fexp2(mrun - mn);
            lrun *= fac;
#pragma unroll
            for (int dd = 0; dd < 2; ++dd)
#pragma unroll
                for (int r = 0; r < 16; ++r) accO[dd][r] *= fac;
            mrun = mn;
        }

        float pA[16], pB[16];
#pragma unroll
        for (int r = 0; r < 16; ++r) pA[r] = fexp2(sA[r] - mrun);
#pragma unroll
        for (int r = 0; r < 16; ++r) pB[r] = fexp2(sB[r] - mrun);
        float a0 = (pA[0] + pA[1]) + (pA[2] + pA[3]);
        float a1 = (pA[4] + pA[5]) + (pA[6] + pA[7]);
        float a2 = (pA[8] + pA[9]) + (pA[10] + pA[11]);
        float a3 = (pA[12] + pA[13]) + (pA[14] + pA[15]);
        float a4 = (pB[0] + pB[1]) + (pB[2] + pB[3]);
        float a5 = (pB[4] + pB[5]) + (pB[6] + pB[7]);
        float a6 = (pB[8] + pB[9]) + (pB[10] + pB[11]);
        float a7 = (pB[12] + pB[13]) + (pB[14] + pB[15]);
        lrun += ((a0 + a1) + (a2 + a3)) + ((a4 + a5) + (a6 + a7));

        // pack to bf16 pairs
        u32 wA[8], wB[8];
#pragma unroll
        for (int k = 0; k < 8; ++k) {
            union { __hip_bfloat162 h2; u32 u; } cv;
            cv.h2 = __float22bfloat162_rn(float2{pA[2 * k], pA[2 * k + 1]});
            wA[k] = cv.u;
            union { __hip_bfloat162 h2; u32 u; } cw;
            cw.h2 = __float22bfloat162_rn(float2{pB[2 * k], pB[2 * k + 1]});
            wB[k] = cw.u;
        }
        // P^T B-fragments via permlane32_swap
        union { u32 u[4]; bf16x8 v; } fr[4];
        {
            u32x2 e0 = __builtin_amdgcn_permlane32_swap(wA[0], wA[2], false, false);
            u32x2 e1 = __builtin_amdgcn_permlane32_swap(wA[1], wA[3], false, false);
            fr[0].u[0] = e0[0]; fr[0].u[1] = e1[0]; fr[0].u[2] = e0[1]; fr[0].u[3] = e1[1];
            u32x2 e2 = __builtin_amdgcn_permlane32_swap(wA[4], wA[6], false, false);
            u32x2 e3 = __builtin_amdgcn_permlane32_swap(wA[5], wA[7], false, false);
            fr[1].u[0] = e2[0]; fr[1].u[1] = e3[0]; fr[1].u[2] = e2[1]; fr[1].u[3] = e3[1];
            u32x2 e4 = __builtin_amdgcn_permlane32_swap(wB[0], wB[2], false, false);
            u32x2 e5 = __builtin_amdgcn_permlane32_swap(wB[1], wB[3], false, false);
            fr[2].u[0] = e4[0]; fr[2].u[1] = e5[0]; fr[2].u[2] = e4[1]; fr[2].u[3] = e5[1];
            u32x2 e6 = __builtin_amdgcn_permlane32_swap(wB[4], wB[6], false, false);
            u32x2 e7 = __builtin_amdgcn_permlane32_swap(wB[5], wB[7], false, false);
            fr[3].u[0] = e6[0]; fr[3].u[1] = e7[0]; fr[3].u[2] = e6[1]; fr[3].u[3] = e7[1];
        }

        // ---- PV: ds_read V fragments (conflict-free) + MFMA cluster ----
        __builtin_amdgcn_s_setprio(1);
#pragma unroll
        for (int dd = 0; dd < 2; ++dd) {
#pragma unroll
            for (int kk = 0; kk < 4; ++kk) {
                bf16x8 vv = *reinterpret_cast<const bf16x8*>(rc + 8192 + kk * 2048 + dd * 1024);
                accO[dd] = __builtin_amdgcn_mfma_f32_32x32x16_bf16(vv, fr[kk].v, accO[dd], 0, 0, 0);
            }
        }
        __builtin_amdgcn_s_setprio(0);

        // all waves done reading buf(cur) -> safe to overwrite with tile t+2
        __builtin_amdgcn_s_barrier();
        if (t + 2 < 16) STAGE_TILE((t + 2) * 64, smem + cur * 16384);
        cur ^= 1;
    }

    // combine per-half sums once (permlane, no LDS)
    {
        u32 lu = __builtin_bit_cast(u32, lrun);
        u32x2 ll = __builtin_amdgcn_permlane32_swap(lu, lu, false, false);
        lrun = __builtin_bit_cast(float, ll[0]) + __builtin_bit_cast(float, ll[1]);
    }

    __syncthreads();   // all waves out of the loop before obuf overlays the buffers

    // epilogue: O^T (d-major in regs) -> LDS [q][d] -> coalesced global store
    typedef bf16 (*ObufT)[32][72];
    ObufT obuf = (ObufT)smem;
    float inv = 1.f / lrun;
#pragma unroll
    for (int dd = 0; dd < 2; ++dd)
#pragma unroll
        for (int r = 0; r < 16; r += 2) {
            int d = dd * 32 + (r & 3) + 8 * (r >> 2) + 4 * (lane >> 5);
            union { __hip_bfloat162 h2; u32 u; } cv;
            cv.h2 = __float22bfloat162_rn(float2{accO[dd][r] * inv, accO[dd][r + 1] * inv});
            *reinterpret_cast<u32*>(&obuf[wave][l31][d]) = cv.u;
        }
    __syncthreads();
    {
        int qr = lane >> 1, hf = lane & 1;
        const bf16* orow = &obuf[wave][qr][hf * 32];
        bf16* gout = Out + ((size_t)b * 4096 + q0 + qr) * 512 + h * 64 + hf * 32;
#pragma unroll
        for (int j = 0; j < 4; ++j) {
            bf16x8 t2 = *reinterpret_cast<const bf16x8*>(orow + j * 8);
            *reinterpret_cast<bf16x8*>(gout + j * 8) = t2;
        }
    }
#undef STAGE_TILE
}

extern "C" void kernel_launch(void* const* d_in, const int* in_sizes, int n_in,
                              void* d_out, int out_size, void* d_ws, size_t ws_size,
                              hipStream_t stream) {
    const float* x      = (const float*)d_in[0];
    const float* q_w    = (const float*)d_in[1];
    const float* q_b    = (const float*)d_in[2];
    const float* kv_w   = (const float*)d_in[3];
    const float* kv_b   = (const float*)d_in[4];
    const float* sr_w   = (const float*)d_in[5];
    const float* sr_b   = (const float*)d_in[6];
    const float* ln_g   = (const float*)d_in[7];
    const float* ln_b   = (const float*)d_in[8];
    const float* proj_w = (const float*)d_in[9];
    const float* proj_b = (const float*)d_in[10];

    char* w = (char*)d_ws;
    bf16* x_bf   = (bf16*)w; w += (size_t)8 * 4096 * 512 * 2;
    bf16* q_bf   = (bf16*)w; w += (size_t)8 * 4096 * 512 * 2;
    bf16* qw_bf  = (bf16*)w; w += (size_t)512 * 512 * 2;
    bf16* kvw_bf = (bf16*)w; w += (size_t)1024 * 512 * 2;
    bf16* srw_bf = (bf16*)w; w += (size_t)512 * 2048 * 2;
    bf16* pjw_bf = (bf16*)w; w += (size_t)512 * 512 * 2;
    float* xsr_f = (float*)w; w += (size_t)8 * 1024 * 512 * 4;
    bf16* xsrb   = (bf16*)w; w += (size_t)8 * 1024 * 512 * 2;
    bf16* k_bf   = (bf16*)w; w += (size_t)8 * 8 * 1024 * 64 * 2;
    bf16* vt_bf  = (bf16*)w; w += (size_t)8 * 8 * 1024 * 64 * 2;
    bf16* ao_bf  = (bf16*)w; w += (size_t)8 * 4096 * 512 * 2;

    cast_k<<<dim3(16384), dim3(256), 0, stream>>>(x, x_bf, 4194304);
    cast_k<<<dim3(256),  dim3(256), 0, stream>>>(q_w, qw_bf, 65536);
    cast_k<<<dim3(512),  dim3(256), 0, stream>>>(kv_w, kvw_bf, 131072);
    cast_k<<<dim3(256),  dim3(256), 0, stream>>>(proj_w, pjw_bf, 65536);
    repack_srw_k<<<dim3(4096), dim3(256), 0, stream>>>(sr_w, srw_bf);

    gemm_k<0><<<dim3(1024), dim3(256), 0, stream>>>(x_bf, qw_bf, q_b, q_bf, nullptr, nullptr, 32768, 512, 512);
    gemm_k<1><<<dim3(256), dim3(256), 0, stream>>>(x_bf, srw_bf, sr_b, nullptr, nullptr, xsr_f, 8192, 512, 2048);
    ln_k<<<dim3(8192), dim3(256), 0, stream>>>(xsr_f, ln_g, ln_b, xsrb);
    gemm_k<2><<<dim3(512), dim3(256), 0, stream>>>(xsrb, kvw_bf, kv_b, k_bf, vt_bf, nullptr, 8192, 1024, 512);
    attn_k<<<dim3(2048), dim3(256), 0, stream>>>(q_bf, k_bf, vt_bf, ao_bf);
    gemm_k<3><<<dim3(1024), dim3(256), 0, stream>>>(ao_bf, pjw_bf, proj_b, nullptr, nullptr, (float*)d_out, 32768, 512, 512);
}